// Round 3
// baseline (120.606 us; speedup 1.0000x reference)
//
#include <hip/hip_runtime.h>

// Diversity2: mean(0.3 * pearson_corr(softmax(o1/T), softmax(o2/T), axis=1))
//
// Identities:
//  (1) corr is invariant to per-row positive scaling and shift -> softmax
//      normalization and max-subtraction drop out: corr(p1,p2) ==
//      corr(exp(o1/T), exp(o2/T)).
//  (2) shift again: x = exp(o/T) - 1 (exact Sterbenz subtraction, exp in
//      [0.78,1.32]) centers x near 0 so fp32 accumulation of
//      {Sx,Sy,Sxx,Syy,Sxy} has no catastrophic cancellation. fp64 only in
//      the per-row epilogue and the final mean.
//
// Structure: ONE fused kernel. 512 blocks x 4 waves (fully resident, one
// residency round). Per-wave barrier-free pipeline: 2 x 8 KB LDS buffers,
// next row staged with 8x global_load_lds(width=16), counted
// `s_waitcnt vmcnt(8)` (never 0 in-loop). Final reduction: each block
// publishes a double partial, release-increments a counter (agent scope);
// the last block acquire-reads all partials via atomic loads and writes out.
// Counter is zeroed each launch by a 4-byte hipMemsetAsync (capturable).
//
// Tail fix vs round 2: when staging the global last row, lanes 58..63 get
// their global ADDRESS clamped to the row start instead of being exec-masked
// out -> always exactly 8 gload_lds per stage, so vmcnt(8) retires precisely
// the current row's loads (exec-masking dropped 2 insts and let compute read
// chunk 3 before it landed).

#define N_ROWS  65536
#define N_C     1000
#define NBLOCKS 512
#define WPB     4           // waves per block
#define RPW     32          // rows per wave: 65536 / (512*4)

__device__ __forceinline__ void gload16(const float* g, float* s) {
    __builtin_amdgcn_global_load_lds(
        (const __attribute__((address_space(1))) void*)g,
        (__attribute__((address_space(3))) void*)s, 16, 0, 0);
}

// Stage one row (both matrices) into an 8 KB LDS buffer.
// Row = 1000 floats = 250 float4, padded to 256 float4 slots per matrix.
// Chunk k=3 lanes 58..63 over-read into the next row (in-bounds) except at
// the global last row, where their address is clamped to the row start.
__device__ __forceinline__ void stage_row(const float* __restrict__ r1,
                                          const float* __restrict__ r2,
                                          bool final_row, float* dst, int lane) {
    const int l4 = lane * 4;
    gload16(r1 + l4,       dst);
    gload16(r1 + 256 + l4, dst + 256);
    gload16(r1 + 512 + l4, dst + 512);
    gload16(r2 + l4,       dst + 1024);
    gload16(r2 + 256 + l4, dst + 1280);
    gload16(r2 + 512 + l4, dst + 1536);
    const float* a3 = r1 + 768 + l4;
    const float* b3 = r2 + 768 + l4;
    if (final_row && lane >= 58) { a3 = r1; b3 = r2; }   // per-lane addr clamp
    gload16(a3, dst + 768);
    gload16(b3, dst + 1792);
}

// Per-row Pearson cost from an LDS buffer (A at buf, B at buf+1024).
__device__ __forceinline__ double row_cost(const float* buf, int lane) {
    const float4* A = reinterpret_cast<const float4*>(buf);
    const float4* B = reinterpret_cast<const float4*>(buf + 1024);
    constexpr float INV_T = 1.0f / 20.0f;
    float sx = 0.f, sy = 0.f, sxx = 0.f, syy = 0.f, sxy = 0.f;
    #pragma unroll
    for (int k = 0; k < 4; ++k) {
        float4 a = A[k * 64 + lane];
        float4 b = B[k * 64 + lane];
        const bool ok = (k < 3) || (lane < 58);
        float av[4] = {a.x, a.y, a.z, a.w};
        float bv[4] = {b.x, b.y, b.z, b.w};
        #pragma unroll
        for (int e = 0; e < 4; ++e) {
            float va = ok ? av[e] : 0.0f;   // zero INPUT for pad slots:
            float vb = ok ? bv[e] : 0.0f;   // exp(0)-1 == 0 contributes nothing
            float x = __expf(va * INV_T) - 1.0f;
            float y = __expf(vb * INV_T) - 1.0f;
            sx += x;  sy += y;
            sxx = fmaf(x, x, sxx);
            syy = fmaf(y, y, syy);
            sxy = fmaf(x, y, sxy);
        }
    }
    #pragma unroll
    for (int off = 32; off; off >>= 1) {
        sx  += __shfl_xor(sx,  off, 64);
        sy  += __shfl_xor(sy,  off, 64);
        sxx += __shfl_xor(sxx, off, 64);
        syy += __shfl_xor(syy, off, 64);
        sxy += __shfl_xor(sxy, off, 64);
    }
    constexpr double invC = 1.0 / (double)N_C;
    double dx = (double)sx, dy = (double)sy;
    double num = (double)sxy - dx * dy * invC;
    double vx  = (double)sxx - dx * dx * invC;
    double vy  = (double)syy - dy * dy * invC;
    return num / sqrt(vx * vy);
}

__global__ __launch_bounds__(256) void div2_fused(
        const float* __restrict__ o1, const float* __restrict__ o2,
        double* __restrict__ ws, unsigned int* __restrict__ cnt,
        float* __restrict__ out) {
    __shared__ float lds[WPB][2][2048];   // 64 KB: per-wave 2 x 8 KB buffers
    __shared__ double dred[WPB];
    __shared__ int slast;

    const int wave = threadIdx.x >> 6;
    const int lane = threadIdx.x & 63;
    const int gw   = blockIdx.x * WPB + wave;
    const long r0  = (long)gw * RPW;

    float* buf0 = &lds[wave][0][0];
    float* buf1 = &lds[wave][1][0];

    const float* row1 = o1 + r0 * (long)N_C;
    const float* row2 = o2 + r0 * (long)N_C;
    stage_row(row1, row2, r0 == (long)N_ROWS - 1, buf0, lane);  // prologue

    double acc = 0.0;
    #pragma unroll 1
    for (int p = 0; p < RPW; ++p) {
        float* cur = (p & 1) ? buf1 : buf0;
        float* nxt = (p & 1) ? buf0 : buf1;
        if (p + 1 < RPW) {
            long nr = r0 + p + 1;
            stage_row(o1 + nr * (long)N_C, o2 + nr * (long)N_C,
                      nr == (long)N_ROWS - 1, nxt, lane);
            // counted wait: current row's 8 loads done, next row's 8 in flight
            asm volatile("s_waitcnt vmcnt(8)" ::: "memory");
        } else {
            asm volatile("s_waitcnt vmcnt(0)" ::: "memory");
        }
        acc += row_cost(cur, lane);
    }

    // ---- block combine ----
    if (lane == 0) dred[wave] = acc;
    __syncthreads();
    if (threadIdx.x == 0) {
        double part = dred[0] + dred[1] + dred[2] + dred[3];
        ws[blockIdx.x] = part;
        unsigned int old = __hip_atomic_fetch_add(cnt, 1u, __ATOMIC_ACQ_REL,
                                                  __HIP_MEMORY_SCOPE_AGENT);
        slast = (old == NBLOCKS - 1);
    }
    __syncthreads();

    // ---- last block: final reduction across all block partials ----
    if (slast) {
        const int t = threadIdx.x;
        double s = 0.0;
        #pragma unroll
        for (int i = 0; i < NBLOCKS / 256; ++i)
            s += __hip_atomic_load(&ws[t + i * 256], __ATOMIC_RELAXED,
                                   __HIP_MEMORY_SCOPE_AGENT);
        #pragma unroll
        for (int off = 32; off; off >>= 1) s += __shfl_xor(s, off, 64);
        if (lane == 0) dred[wave] = s;
        __syncthreads();
        if (t == 0)
            out[0] = (float)((dred[0] + dred[1] + dred[2] + dred[3]) *
                             (0.3 / (double)N_ROWS));
    }
}

extern "C" void kernel_launch(void* const* d_in, const int* in_sizes, int n_in,
                              void* d_out, int out_size, void* d_ws, size_t ws_size,
                              hipStream_t stream) {
    const float* o1 = (const float*)d_in[0];
    const float* o2 = (const float*)d_in[1];
    // d_in[2] (targets) is unused by the reference.
    float* out = (float*)d_out;
    double* ws = (double*)d_ws;                       // [0..511] block partials
    unsigned int* cnt = (unsigned int*)((char*)d_ws + NBLOCKS * sizeof(double));

    // zero the completion counter every call (graph-capturable async memset)
    hipMemsetAsync((void*)cnt, 0, sizeof(unsigned int), stream);

    div2_fused<<<NBLOCKS, 256, 0, stream>>>(o1, o2, ws, cnt, out);
}